// Round 1
// baseline (1076.076 us; speedup 1.0000x reference)
//
#include <hip/hip_runtime.h>
#include <math.h>

#define TS   64
#define HALO 3
#define LD   (TS + 2*HALO)   // 70
#define LDP  (LD + 1)        // 71, padded LDS stride
#define NUM_ITER 40

__device__ __forceinline__ float frelu(float x) { return x > 0.f ? x : 0.f; }

// One full iteration: img_out = erode(img_in);
// skel += relu(delta - skel*delta) with delta = relu(img_out - dilate(erode(img_out)))
__global__ __launch_bounds__(256)
void iter_kernel(const float* __restrict__ img_in, float* __restrict__ img_out,
                 float* __restrict__ skel, int H, int W)
{
    __shared__ float sA[LD * LDP];   // img (halo 3), later reused for e2
    __shared__ float sB[LD * LDP];   // e1 = erode(img)

    const int tid = threadIdx.x;
    const int x0 = blockIdx.x * TS;
    const int y0 = blockIdx.y * TS;
    const size_t base = (size_t)blockIdx.z * H * W;

    // ---- load img tile with halo 3; outside image = +inf (min-pool pad) ----
    for (int i = tid; i < LD * LD; i += 256) {
        int r = i / LD, c = i - r * LD;
        int gy = y0 - HALO + r, gx = x0 - HALO + c;
        float v = INFINITY;
        if (gy >= 0 && gy < H && gx >= 0 && gx < W)
            v = img_in[base + (size_t)gy * W + gx];
        sA[r * LDP + c] = v;
    }
    __syncthreads();

    // ---- e1 = erode(img) on halo-2 region; forced +inf outside image ----
    for (int i = tid; i < (LD - 2) * (LD - 2); i += 256) {
        int r = 1 + i / (LD - 2), c = 1 + i % (LD - 2);
        int gy = y0 - HALO + r, gx = x0 - HALO + c;
        float v = INFINITY;
        if (gy >= 0 && gy < H && gx >= 0 && gx < W) {
            float cc = sA[r * LDP + c];
            float up = sA[(r - 1) * LDP + c];
            float dn = sA[(r + 1) * LDP + c];
            float lf = sA[r * LDP + c - 1];
            float rt = sA[r * LDP + c + 1];
            v = fminf(fminf(fminf(up, dn), fminf(lf, rt)), cc);
        }
        sB[r * LDP + c] = v;
    }
    __syncthreads();

    // ---- e2 = erode(e1) on halo-1 region; outside image = -inf (max-pool pad) ----
    // (written into sA, img no longer needed)
    for (int i = tid; i < (LD - 4) * (LD - 4); i += 256) {
        int r = 2 + i / (LD - 4), c = 2 + i % (LD - 4);
        int gy = y0 - HALO + r, gx = x0 - HALO + c;
        float v = -INFINITY;
        if (gy >= 0 && gy < H && gx >= 0 && gx < W) {
            float cc = sB[r * LDP + c];
            float up = sB[(r - 1) * LDP + c];
            float dn = sB[(r + 1) * LDP + c];
            float lf = sB[r * LDP + c - 1];
            float rt = sB[r * LDP + c + 1];
            v = fminf(fminf(fminf(up, dn), fminf(lf, rt)), cc);
        }
        sA[r * LDP + c] = v;
    }
    __syncthreads();

    // ---- interior: d = dilate3x3(e2); delta = relu(e1 - d); skel update; img_out = e1 ----
    const int tx = tid & 63;
    const int ty = tid >> 6;     // 0..3
    for (int yy = ty; yy < TS; yy += 4) {
        int r = HALO + yy, c = HALO + tx;
        float d = -INFINITY;
        #pragma unroll
        for (int dy = -1; dy <= 1; ++dy) {
            const float* row = &sA[(r + dy) * LDP + c];
            d = fmaxf(d, fmaxf(fmaxf(row[-1], row[0]), row[1]));
        }
        float e1v = sB[r * LDP + c];
        float delta = frelu(e1v - d);
        size_t g = base + (size_t)(y0 + yy) * W + (x0 + tx);
        float s = skel[g];
        skel[g] = s + frelu(delta - s * delta);
        img_out[g] = e1v;
    }
}

// skel = relu(img - dilate(erode(img)))  (img unchanged)
__global__ __launch_bounds__(256)
void init_kernel(const float* __restrict__ img, float* __restrict__ skel, int H, int W)
{
    __shared__ float sA[LD * LDP];   // img
    __shared__ float sB[LD * LDP];   // e = erode(img)

    const int tid = threadIdx.x;
    const int x0 = blockIdx.x * TS;
    const int y0 = blockIdx.y * TS;
    const size_t base = (size_t)blockIdx.z * H * W;

    for (int i = tid; i < LD * LD; i += 256) {
        int r = i / LD, c = i - r * LD;
        int gy = y0 - HALO + r, gx = x0 - HALO + c;
        float v = INFINITY;
        if (gy >= 0 && gy < H && gx >= 0 && gx < W)
            v = img[base + (size_t)gy * W + gx];
        sA[r * LDP + c] = v;
    }
    __syncthreads();

    // e = erode(img) on halo-1 region; outside image = -inf (dilate pad)
    for (int i = tid; i < (LD - 4) * (LD - 4); i += 256) {
        int r = 2 + i / (LD - 4), c = 2 + i % (LD - 4);
        int gy = y0 - HALO + r, gx = x0 - HALO + c;
        float v = -INFINITY;
        if (gy >= 0 && gy < H && gx >= 0 && gx < W) {
            float cc = sA[r * LDP + c];
            float up = sA[(r - 1) * LDP + c];
            float dn = sA[(r + 1) * LDP + c];
            float lf = sA[r * LDP + c - 1];
            float rt = sA[r * LDP + c + 1];
            v = fminf(fminf(fminf(up, dn), fminf(lf, rt)), cc);
        }
        sB[r * LDP + c] = v;
    }
    __syncthreads();

    const int tx = tid & 63;
    const int ty = tid >> 6;
    for (int yy = ty; yy < TS; yy += 4) {
        int r = HALO + yy, c = HALO + tx;
        float d = -INFINITY;
        #pragma unroll
        for (int dy = -1; dy <= 1; ++dy) {
            const float* row = &sB[(r + dy) * LDP + c];
            d = fmaxf(d, fmaxf(fmaxf(row[-1], row[0]), row[1]));
        }
        float iv = sA[r * LDP + c];
        size_t g = base + (size_t)(y0 + yy) * W + (x0 + tx);
        skel[g] = frelu(iv - d);
    }
}

extern "C" void kernel_launch(void* const* d_in, const int* in_sizes, int n_in,
                              void* d_out, int out_size, void* d_ws, size_t ws_size,
                              hipStream_t stream)
{
    const float* img = (const float*)d_in[0];
    float* skel = (float*)d_out;
    const int H = 1024, W = 1024;
    const int total = in_sizes[0];
    const int B = total / (H * W);

    float* bufA = (float*)d_ws;
    float* bufB = bufA + (size_t)total;

    dim3 grid(W / TS, H / TS, B), block(256);

    // skel_0 = relu(img - open(img))
    init_kernel<<<grid, block, 0, stream>>>(img, skel, H, W);

    // 40 iterations: img = erode(img); skel-update
    const float* src = img;
    float* dst = bufA;
    for (int t = 0; t < NUM_ITER; ++t) {
        iter_kernel<<<grid, block, 0, stream>>>(src, dst, skel, H, W);
        src = dst;
        dst = (dst == bufA) ? bufB : bufA;
    }
}

// Round 2
// 844.002 us; speedup vs baseline: 1.2750x; 1.2750x over previous
//
#include <hip/hip_runtime.h>
#include <math.h>

#define TS    64
#define HALO  4
#define LDR   72            // TS + 2*HALO rows
#define LDP   76            // row stride in floats (304B, 16B-aligned, bank step 12)
#define GUARD 4             // left guard columns so c=-4 reads stay in-bounds
#define LDS_SZ (LDR*LDP + 16)
#define NUM_ITER 40

__device__ __forceinline__ float4 f4min(float4 a, float4 b) {
    return make_float4(fminf(a.x,b.x), fminf(a.y,b.y), fminf(a.z,b.z), fminf(a.w,b.w));
}
__device__ __forceinline__ float4 f4max(float4 a, float4 b) {
    return make_float4(fmaxf(a.x,b.x), fmaxf(a.y,b.y), fmaxf(a.z,b.z), fmaxf(a.w,b.w));
}
__device__ __forceinline__ float frelu(float x) { return x > 0.f ? x : 0.f; }

__device__ __forceinline__ float4 ld4(const float* s, int r, int c) {
    return *(const float4*)&s[r*LDP + GUARD + c];
}
__device__ __forceinline__ void st4(float* s, int r, int c, float4 v) {
    *(float4*)&s[r*LDP + GUARD + c] = v;
}

// Load 72x72 tile (halo 4) of img into sA; +inf outside image (min-pool pad).
__device__ __forceinline__ void load_tile(const float* __restrict__ img, size_t base,
                                          int x0, int y0, int H, int W,
                                          float* sA, int tid)
{
    for (int i = tid; i < 72*18; i += 256) {
        int r = i / 18, b = i - (i/18)*18;
        int c = 4*b;
        int gy = y0 - HALO + r, gx0 = x0 - HALO + c;
        float4 v;
        if ((unsigned)gy < (unsigned)H && (unsigned)gx0 <= (unsigned)(W-4)) {
            v = *(const float4*)&img[base + (size_t)gy*W + gx0];
        } else if ((unsigned)gy < (unsigned)H) {
            const float* row = &img[base + (size_t)gy*W];
            v.x = ((unsigned)(gx0+0) < (unsigned)W) ? row[gx0+0] : INFINITY;
            v.y = ((unsigned)(gx0+1) < (unsigned)W) ? row[gx0+1] : INFINITY;
            v.z = ((unsigned)(gx0+2) < (unsigned)W) ? row[gx0+2] : INFINITY;
            v.w = ((unsigned)(gx0+3) < (unsigned)W) ? row[gx0+3] : INFINITY;
        } else {
            v = make_float4(INFINITY, INFINITY, INFINITY, INFINITY);
        }
        st4(sA, r, c, v);
    }
}

// Cross-erode of src -> dst over rows [r0..r1], all 18 col-blocks.
// Elements whose global coords fall outside the image are forced to `force`.
__device__ __forceinline__ void erode_phase(const float* src, float* dst,
                                            int r0, int nrows, float force,
                                            int x0, int y0, int H, int W, int tid)
{
    for (int i = tid; i < nrows*18; i += 256) {
        int r = r0 + i/18, b = i - (i/18)*18;
        int c = 4*b;
        float4 A = ld4(src, r, c);
        float4 U = ld4(src, r-1, c);
        float4 D = ld4(src, r+1, c);
        float4 L = ld4(src, r, c-4);
        float4 R = ld4(src, r, c+4);
        float4 vm = f4min(f4min(U, D), A);      // includes center
        float4 h  = make_float4(fminf(L.w, A.y), fminf(A.x, A.z),
                                fminf(A.y, A.w), fminf(A.z, R.x));
        float4 e  = f4min(vm, h);
        int gy = y0 - HALO + r, gx0 = x0 - HALO + c;
        bool iny = (unsigned)gy < (unsigned)H;
        e.x = (iny && (unsigned)(gx0+0) < (unsigned)W) ? e.x : force;
        e.y = (iny && (unsigned)(gx0+1) < (unsigned)W) ? e.y : force;
        e.z = (iny && (unsigned)(gx0+2) < (unsigned)W) ? e.z : force;
        e.w = (iny && (unsigned)(gx0+3) < (unsigned)W) ? e.w : force;
        st4(dst, r, c, e);
    }
}

// 3x3 dilate of s at (r, c..c+3), separable vertical-then-horizontal max.
__device__ __forceinline__ float4 dilate4(const float* s, int r, int c)
{
    float4 Lv = f4max(f4max(ld4(s, r-1, c-4), ld4(s, r+1, c-4)), ld4(s, r, c-4));
    float4 Av = f4max(f4max(ld4(s, r-1, c  ), ld4(s, r+1, c  )), ld4(s, r, c  ));
    float4 Rv = f4max(f4max(ld4(s, r-1, c+4), ld4(s, r+1, c+4)), ld4(s, r, c+4));
    return make_float4(fmaxf(fmaxf(Lv.w, Av.x), Av.y),
                       fmaxf(fmaxf(Av.x, Av.y), Av.z),
                       fmaxf(fmaxf(Av.y, Av.z), Av.w),
                       fmaxf(fmaxf(Av.z, Av.w), Rv.x));
}

// One iteration: img_out = erode(img_in); skel update with
// delta = relu(e1 - dilate(erode(e1))).
__global__ __launch_bounds__(256)
void iter_kernel(const float* __restrict__ img_in, float* __restrict__ img_out,
                 float* __restrict__ skel, int H, int W)
{
    __shared__ __align__(16) float sA[LDS_SZ];
    __shared__ __align__(16) float sB[LDS_SZ];
    const int tid = threadIdx.x;
    const int x0 = blockIdx.x * TS, y0 = blockIdx.y * TS;
    const size_t base = (size_t)blockIdx.z * H * W;

    load_tile(img_in, base, x0, y0, H, W, sA, tid);
    __syncthreads();

    // e1 = erode(img), rows [2..69]; +inf outside (feeds another erosion)
    erode_phase(sA, sB, 2, 68, INFINITY, x0, y0, H, W, tid);
    __syncthreads();

    // e2 = erode(e1), rows [3..68]; -inf outside (feeds dilation)
    erode_phase(sB, sA, 3, 66, -INFINITY, x0, y0, H, W, tid);
    __syncthreads();

    // interior rows [4..67], col-blocks b=1..16
    for (int i = tid; i < 64*16; i += 256) {
        int r = 4 + (i >> 4);
        int c = 4*(1 + (i & 15));
        float4 d   = dilate4(sA, r, c);
        float4 e1v = ld4(sB, r, c);
        size_t g = base + (size_t)(y0 - HALO + r)*W + (x0 - HALO + c);
        float4 s = *(const float4*)&skel[g];
        float4 dl = make_float4(frelu(e1v.x - d.x), frelu(e1v.y - d.y),
                                frelu(e1v.z - d.z), frelu(e1v.w - d.w));
        float4 ns = make_float4(s.x + frelu(dl.x - s.x*dl.x),
                                s.y + frelu(dl.y - s.y*dl.y),
                                s.z + frelu(dl.z - s.z*dl.z),
                                s.w + frelu(dl.w - s.w*dl.w));
        *(float4*)&skel[g]    = ns;
        *(float4*)&img_out[g] = e1v;
    }
}

// skel = relu(img - dilate(erode(img)))
__global__ __launch_bounds__(256)
void init_kernel(const float* __restrict__ img, float* __restrict__ skel, int H, int W)
{
    __shared__ __align__(16) float sA[LDS_SZ];
    __shared__ __align__(16) float sB[LDS_SZ];
    const int tid = threadIdx.x;
    const int x0 = blockIdx.x * TS, y0 = blockIdx.y * TS;
    const size_t base = (size_t)blockIdx.z * H * W;

    load_tile(img, base, x0, y0, H, W, sA, tid);
    __syncthreads();

    // e = erode(img), rows [3..68]; -inf outside (feeds dilation)
    erode_phase(sA, sB, 3, 66, -INFINITY, x0, y0, H, W, tid);
    __syncthreads();

    for (int i = tid; i < 64*16; i += 256) {
        int r = 4 + (i >> 4);
        int c = 4*(1 + (i & 15));
        float4 d  = dilate4(sB, r, c);
        float4 iv = ld4(sA, r, c);
        size_t g = base + (size_t)(y0 - HALO + r)*W + (x0 - HALO + c);
        float4 o = make_float4(frelu(iv.x - d.x), frelu(iv.y - d.y),
                               frelu(iv.z - d.z), frelu(iv.w - d.w));
        *(float4*)&skel[g] = o;
    }
}

extern "C" void kernel_launch(void* const* d_in, const int* in_sizes, int n_in,
                              void* d_out, int out_size, void* d_ws, size_t ws_size,
                              hipStream_t stream)
{
    const float* img = (const float*)d_in[0];
    float* skel = (float*)d_out;
    const int H = 1024, W = 1024;
    const int total = in_sizes[0];
    const int B = total / (H * W);

    float* bufA = (float*)d_ws;
    float* bufB = bufA + (size_t)total;

    dim3 grid(W / TS, H / TS, B), block(256);

    init_kernel<<<grid, block, 0, stream>>>(img, skel, H, W);

    const float* src = img;
    float* dst = bufA;
    for (int t = 0; t < NUM_ITER; ++t) {
        iter_kernel<<<grid, block, 0, stream>>>(src, dst, skel, H, W);
        src = dst;
        dst = (dst == bufA) ? bufB : bufA;
    }
}

// Round 3
// 782.095 us; speedup vs baseline: 1.3759x; 1.0792x over previous
//
#include <hip/hip_runtime.h>
#include <math.h>

#define WID 1024
#define HEI 1024
#define BH 2            // output rows per wave
#define NUM_ITER 40

struct Row { float4 s[4]; };   // lane l holds cols [16l, 16l+16): 4 consecutive float4

__device__ __forceinline__ float4 f4min(float4 a, float4 b){
    return make_float4(fminf(a.x,b.x),fminf(a.y,b.y),fminf(a.z,b.z),fminf(a.w,b.w));
}
__device__ __forceinline__ float4 f4max(float4 a, float4 b){
    return make_float4(fmaxf(a.x,b.x),fmaxf(a.y,b.y),fmaxf(a.z,b.z),fmaxf(a.w,b.w));
}
__device__ __forceinline__ float4 f4c(float v){ return make_float4(v,v,v,v); }
__device__ __forceinline__ float frelu(float x){ return fmaxf(x, 0.f); }

__device__ __forceinline__ Row row_load(const float* rowbase, int lane){
    Row r; const float4* q = (const float4*)rowbase + lane*4;
    r.s[0]=q[0]; r.s[1]=q[1]; r.s[2]=q[2]; r.s[3]=q[3]; return r;
}
__device__ __forceinline__ Row row_load_or(const float* base, int row, int lane, float pad){
    if ((unsigned)row < (unsigned)HEI) return row_load(base + (size_t)row*WID, lane);
    Row r; r.s[0]=r.s[1]=r.s[2]=r.s[3]=f4c(pad); return r;
}
__device__ __forceinline__ void row_store(float* rowbase, int lane, const Row& r){
    float4* q = (float4*)rowbase + lane*4;
    q[0]=r.s[0]; q[1]=r.s[1]; q[2]=r.s[2]; q[3]=r.s[3];
}

// plus-shaped (cross) erode of middle row ce, using up/dn rows.
// Horizontal pad at image edges = +inf (erosion identity).
// If !valid (output row outside image), force whole row to fv.
__device__ __forceinline__ Row erode_row(const Row& up, const Row& ce, const Row& dn,
                                         int lane, bool valid, float fv){
    float lw = __shfl_up(ce.s[3].w, 1, 64);     // col 16l-1 from lane-1
    float rx = __shfl_down(ce.s[0].x, 1, 64);   // col 16l+16 from lane+1
    if (lane == 0)  lw = INFINITY;
    if (lane == 63) rx = INFINITY;
    Row res;
    #pragma unroll
    for (int s=0;s<4;s++){
        float4 v = f4min(f4min(up.s[s], dn.s[s]), ce.s[s]);
        float l0 = (s==0)? lw : ce.s[s-1].w;
        float r3 = (s==3)? rx : ce.s[s+1].x;
        float4 h = make_float4(fminf(l0,        ce.s[s].y),
                               fminf(ce.s[s].x, ce.s[s].z),
                               fminf(ce.s[s].y, ce.s[s].w),
                               fminf(ce.s[s].z, r3));
        res.s[s] = f4min(v, h);
    }
    if (!valid){ res.s[0]=res.s[1]=res.s[2]=res.s[3]=f4c(fv); }
    return res;
}

// horizontal 3-max (includes center) of vm; pad -inf at image edges.
__device__ __forceinline__ Row hmax3(const Row& vm, int lane){
    float lw = __shfl_up(vm.s[3].w, 1, 64);
    float rx = __shfl_down(vm.s[0].x, 1, 64);
    if (lane == 0)  lw = -INFINITY;
    if (lane == 63) rx = -INFINITY;
    Row res;
    #pragma unroll
    for (int s=0;s<4;s++){
        float l0 = (s==0)? lw : vm.s[s-1].w;
        float r3 = (s==3)? rx : vm.s[s+1].x;
        float4 a = vm.s[s];
        res.s[s] = make_float4(fmaxf(fmaxf(l0,  a.x), a.y),
                               fmaxf(fmaxf(a.x, a.y), a.z),
                               fmaxf(fmaxf(a.y, a.z), a.w),
                               fmaxf(fmaxf(a.z, a.w), r3));
    }
    return res;
}

// One iteration. Pipeline (head row i): load img[i]; e1[i-1]=erode(img);
// e2[i-2]=erode(e1); dil[i-3]=dilate3x3(e2); delta=relu(e1[i-3]-dil);
// skel update + img_out=e1 at row i-3.
__global__ __launch_bounds__(256, 2)
void iter_kernel(const float* __restrict__ img_in, float* __restrict__ img_out,
                 float* __restrict__ skel, int bandsPerImg)
{
    const int lane = threadIdx.x & 63;
    const int gw   = blockIdx.x*4 + (threadIdx.x >> 6);
    const int b    = gw / bandsPerImg;
    const int band = gw - b*bandsPerImg;
    const int r0   = band*BH;
    const size_t base = (size_t)b*HEI*WID;
    const float* src = img_in + base;
    float* outi = img_out + base;
    float* outs = skel + base;

    Row imgw[4], e1w[3], e2w[3], sk0, sk1;

    imgw[0] = row_load_or(src, r0-3, lane, INFINITY);   // row r0-3 -> slot 0
    imgw[1] = row_load_or(src, r0-2, lane, INFINITY);   // row r0-2 -> slot 1

    #pragma unroll
    for (int st=0; st<8; ++st){
        const int i = r0 - 3 + st;
        if (st>=1 && st<=6)                      // prefetch row i+1 (slot (st+1)&3)
            imgw[(st+1)&3] = row_load_or(src, i+1, lane, INFINITY);
        if (st==4) sk0 = row_load(outs + (size_t)r0*WID,     lane);
        if (st==5) sk1 = row_load(outs + (size_t)(r0+1)*WID, lane);

        if (st>=2){   // e1[i-1] from img rows i-2,i-1,i
            const int r = i-1;
            e1w[st%3] = erode_row(imgw[(st-2)&3], imgw[(st-1)&3], imgw[st&3],
                                  lane, (unsigned)r<(unsigned)HEI, INFINITY);
        }
        if (st>=4){   // e2[i-2] from e1 rows i-3,i-2,i-1; out rows forced -inf (dilate pad)
            const int r = i-2;
            e2w[st%3] = erode_row(e1w[(st-2)%3], e1w[(st-1)%3], e1w[st%3],
                                  lane, (unsigned)r<(unsigned)HEI, -INFINITY);
        }
        if (st>=6){   // output row ro = i-3 (= r0 + st-6), always in-image
            const int ro = i-3;
            Row vm;
            #pragma unroll
            for (int s=0;s<4;s++)
                vm.s[s] = f4max(f4max(e2w[(st-2)%3].s[s], e2w[(st-1)%3].s[s]),
                                e2w[st%3].s[s]);
            Row dil = hmax3(vm, lane);
            const Row& e1o = e1w[(st-2)%3];   // e1 row i-3
            const Row& cur = (st==6)? sk0 : sk1;
            Row ns;
            #pragma unroll
            for (int s=0;s<4;s++){
                float4 e = e1o.s[s], d = dil.s[s], c = cur.s[s];
                float4 dl = make_float4(frelu(e.x-d.x), frelu(e.y-d.y),
                                        frelu(e.z-d.z), frelu(e.w-d.w));
                ns.s[s] = make_float4(c.x + frelu(dl.x - c.x*dl.x),
                                      c.y + frelu(dl.y - c.y*dl.y),
                                      c.z + frelu(dl.z - c.z*dl.z),
                                      c.w + frelu(dl.w - c.w*dl.w));
            }
            row_store(outs + (size_t)ro*WID, lane, ns);
            row_store(outi + (size_t)ro*WID, lane, e1o);
        }
    }
}

// skel = relu(img - dilate(erode(img))); img untouched.
__global__ __launch_bounds__(256, 2)
void init_kernel(const float* __restrict__ img, float* __restrict__ skel, int bandsPerImg)
{
    const int lane = threadIdx.x & 63;
    const int gw   = blockIdx.x*4 + (threadIdx.x >> 6);
    const int b    = gw / bandsPerImg;
    const int band = gw - b*bandsPerImg;
    const int r0   = band*BH;
    const size_t base = (size_t)b*HEI*WID;
    const float* src = img + base;
    float* outs = skel + base;

    Row imgw[4], ew[3];

    imgw[0] = row_load_or(src, r0-2, lane, INFINITY);
    imgw[1] = row_load_or(src, r0-1, lane, INFINITY);

    #pragma unroll
    for (int st=0; st<6; ++st){
        const int i = r0 - 2 + st;
        if (st>=1 && st<=4)
            imgw[(st+1)&3] = row_load_or(src, i+1, lane, INFINITY);

        if (st>=2){   // e[i-1] = erode(img); out rows forced -inf (feeds dilate)
            const int r = i-1;
            ew[st%3] = erode_row(imgw[(st-2)&3], imgw[(st-1)&3], imgw[st&3],
                                 lane, (unsigned)r<(unsigned)HEI, -INFINITY);
        }
        if (st>=4){   // output row ro = i-2
            const int ro = i-2;
            Row vm;
            #pragma unroll
            for (int s=0;s<4;s++)
                vm.s[s] = f4max(f4max(ew[(st-2)%3].s[s], ew[(st-1)%3].s[s]),
                                ew[st%3].s[s]);
            Row dil = hmax3(vm, lane);
            const Row& im = imgw[(st-2)&3];   // img row i-2
            Row o;
            #pragma unroll
            for (int s=0;s<4;s++){
                float4 a = im.s[s], d = dil.s[s];
                o.s[s] = make_float4(frelu(a.x-d.x), frelu(a.y-d.y),
                                     frelu(a.z-d.z), frelu(a.w-d.w));
            }
            row_store(outs + (size_t)ro*WID, lane, o);
        }
    }
}

extern "C" void kernel_launch(void* const* d_in, const int* in_sizes, int n_in,
                              void* d_out, int out_size, void* d_ws, size_t ws_size,
                              hipStream_t stream)
{
    const float* img = (const float*)d_in[0];
    float* skel = (float*)d_out;
    const int total = in_sizes[0];
    const int B = total / (HEI*WID);
    const int bandsPerImg = HEI / BH;              // 512
    const int waves = B * bandsPerImg;             // 2048 for B=4
    const int grid = waves / 4;                    // 4 waves per 256-thread block

    float* bufA = (float*)d_ws;
    float* bufB = bufA + (size_t)total;

    init_kernel<<<grid, 256, 0, stream>>>(img, skel, bandsPerImg);

    const float* src = img;
    float* dst = bufA;
    for (int t = 0; t < NUM_ITER; ++t) {
        iter_kernel<<<grid, 256, 0, stream>>>(src, dst, skel, bandsPerImg);
        src = dst;
        dst = (dst == bufA) ? bufB : bufA;
    }
}

// Round 4
// 378.788 us; speedup vs baseline: 2.8408x; 2.0647x over previous
//
#include <hip/hip_runtime.h>
#include <math.h>

#define WID 1024
#define HEI 1024
#define GUARD 4

__device__ __forceinline__ float4 f4min(float4 a, float4 b){
    return make_float4(fminf(a.x,b.x),fminf(a.y,b.y),fminf(a.z,b.z),fminf(a.w,b.w));
}
__device__ __forceinline__ float4 f4max(float4 a, float4 b){
    return make_float4(fmaxf(a.x,b.x),fmaxf(a.y,b.y),fmaxf(a.z,b.z),fmaxf(a.w,b.w));
}
__device__ __forceinline__ float4 f4c(float v){ return make_float4(v,v,v,v); }
__device__ __forceinline__ float frelu(float x){ return fmaxf(x, 0.f); }

// Fused K-iteration pass. Input img = E^{t0}; performs ops t0..t0+K-1:
//   for j=0..K-1: E^{t0+j+1} = erode(E^{t0+j});
//                 delta = relu(E^{t0+j} - dilate(E^{t0+j+1})); skel update.
// Writes skel tile and (optionally) E^{t0+K} as the next pass's img.
// H = loaded halo (multiple of 4, >= K+1 with >=1 col margin for edge-error front).
template<int K, int H>
__global__ __launch_bounds__(256)
void pass_kernel(const float* __restrict__ img_in, float* __restrict__ img_out,
                 float* __restrict__ skel, int readSkel, int writeImg)
{
    constexpr int WIDTH  = 64 + 2*H;       // loaded tile width/height (floats)
    constexpr int NF4    = WIDTH/4;
    constexpr int ROWS   = WIDTH;
    constexpr int STRIDE = WIDTH + 12;     // 16B-aligned, +4 bank phase per row
    __shared__ __align__(16) float sA[ROWS*STRIDE];
    __shared__ __align__(16) float sB[ROWS*STRIDE];

    const int tid = threadIdx.x;
    const int x0 = blockIdx.x*64, y0 = blockIdx.y*64;
    const size_t base = (size_t)blockIdx.z*HEI*WID;
    const float* src = img_in + base;

    #define LD4(s,r,c)   (*(const float4*)&(s)[(r)*STRIDE + GUARD + (c)])
    #define ST4(s,r,c,v) (*(float4*)&(s)[(r)*STRIDE + GUARD + (c)] = (v))

    // ---- load E^{t0} tile (halo H) + init +inf guard columns in BOTH buffers ----
    for (int i = tid; i < ROWS*(NF4+2); i += 256) {
        int r = i/(NF4+2), bb = i - (i/(NF4+2))*(NF4+2) - 1;   // bb in [-1, NF4]
        int c = 4*bb;
        if (bb < 0 || bb >= NF4) {
            float4 g = f4c(INFINITY);
            ST4(sA, r, c, g);
            ST4(sB, r, c, g);
        } else {
            int gy = y0 - H + r, gx = x0 - H + c;     // gx is 4-aligned, never straddles
            float4 v = ((unsigned)gy < (unsigned)HEI && (unsigned)gx <= (unsigned)(WID-4))
                     ? *(const float4*)&src[(size_t)gy*WID + gx] : f4c(INFINITY);
            ST4(sA, r, c, v);
        }
    }

    // ---- skel accumulator tile in registers: item idx=tid+256p -> row idx>>4, f4col idx&15
    float4 sk[4];
    #pragma unroll
    for (int p = 0; p < 4; ++p) {
        int idx = tid + 256*p;
        int ro = idx >> 4, bb = idx & 15;
        size_t g = base + (size_t)(y0+ro)*WID + x0 + 4*bb;
        sk[p] = readSkel ? *(const float4*)&skel[g] : f4c(0.f);
    }
    __syncthreads();

    float* cur = sA;     // holds E^{t0+j}
    float* oth = sB;

    #pragma unroll 1
    for (int j = 0; j < K; ++j) {
        // ---- erode cur -> oth on rows [j+1, ROWS-1-j), all columns ----
        const int nr = ROWS - 2*(j+1);
        for (int i = tid; i < nr*NF4; i += 256) {
            int r = j+1 + i/NF4, bb = i - (i/NF4)*NF4;
            int c = 4*bb;
            float4 A = LD4(cur,r,c), U = LD4(cur,r-1,c), D = LD4(cur,r+1,c);
            float4 L = LD4(cur,r,c-4), R = LD4(cur,r,c+4);
            float4 vm = f4min(f4min(U, D), A);
            float4 h  = make_float4(fminf(L.w, A.y), fminf(A.x, A.z),
                                    fminf(A.y, A.w), fminf(A.z, R.x));
            float4 e  = f4min(vm, h);
            int gy = y0 - H + r, gx = x0 - H + c;
            if (!((unsigned)gy < (unsigned)HEI && (unsigned)gx <= (unsigned)(WID-4)))
                e = f4c(INFINITY);                      // min-pool pad semantics
            ST4(oth, r, c, e);
        }
        __syncthreads();

        // ---- op t0+j: d = dilate3x3(oth) with -inf outside image; e1 = cur; skel update
        #pragma unroll
        for (int p = 0; p < 4; ++p) {
            int idx = tid + 256*p;
            int ro = idx >> 4, bb = idx & 15;
            int r = H + ro, c = H + 4*bb;
            int gy = y0 + ro, gx = x0 + 4*bb;
            bool up_ok = (gy >= 1), dn_ok = (gy <= HEI-2);
            float4 ninf = f4c(-INFINITY);

            float4 Lu = LD4(oth,r-1,c-4); if (!up_ok) Lu = ninf;
            float4 Ld = LD4(oth,r+1,c-4); if (!dn_ok) Ld = ninf;
            float4 Lv = LD4(oth,r,  c-4);
            float4 Au = LD4(oth,r-1,c  ); if (!up_ok) Au = ninf;
            float4 Ad = LD4(oth,r+1,c  ); if (!dn_ok) Ad = ninf;
            float4 Av = LD4(oth,r,  c  );
            float4 Ru = LD4(oth,r-1,c+4); if (!up_ok) Ru = ninf;
            float4 Rd = LD4(oth,r+1,c+4); if (!dn_ok) Rd = ninf;
            float4 Rv = LD4(oth,r,  c+4);

            float4 Lm = f4max(f4max(Lu, Ld), Lv);
            float4 Am = f4max(f4max(Au, Ad), Av);
            float4 Rm = f4max(f4max(Ru, Rd), Rv);
            float l0 = (gx >= 1)          ? Lm.w : -INFINITY;
            float r3 = (gx + 4 <= WID-1)  ? Rm.x : -INFINITY;
            float4 d = make_float4(fmaxf(fmaxf(l0,   Am.x), Am.y),
                                   fmaxf(fmaxf(Am.x, Am.y), Am.z),
                                   fmaxf(fmaxf(Am.y, Am.z), Am.w),
                                   fmaxf(fmaxf(Am.z, Am.w), r3));
            float4 e1 = LD4(cur, r, c);
            float4 dl = make_float4(frelu(e1.x-d.x), frelu(e1.y-d.y),
                                    frelu(e1.z-d.z), frelu(e1.w-d.w));
            float4 s = sk[p];
            sk[p] = make_float4(s.x + frelu(dl.x - s.x*dl.x),
                                s.y + frelu(dl.y - s.y*dl.y),
                                s.z + frelu(dl.z - s.z*dl.z),
                                s.w + frelu(dl.w - s.w*dl.w));
        }
        __syncthreads();
        float* t = cur; cur = oth; oth = t;   // cur now holds E^{t0+j+1}
    }

    // ---- write skel tile; optionally write E^{t0+K} (next pass's img) ----
    #pragma unroll
    for (int p = 0; p < 4; ++p) {
        int idx = tid + 256*p;
        int ro = idx >> 4, bb = idx & 15;
        size_t g = base + (size_t)(y0+ro)*WID + x0 + 4*bb;
        *(float4*)&skel[g] = sk[p];
        if (writeImg) {
            float4 v = LD4(cur, H + ro, H + 4*bb);
            *(float4*)&img_out[g] = v;
        }
    }
    #undef LD4
    #undef ST4
}

extern "C" void kernel_launch(void* const* d_in, const int* in_sizes, int n_in,
                              void* d_out, int out_size, void* d_ws, size_t ws_size,
                              hipStream_t stream)
{
    const float* img = (const float*)d_in[0];
    float* skel = (float*)d_out;
    const int total = in_sizes[0];
    const int B = total / (HEI*WID);

    float* bufA = (float*)d_ws;
    float* bufB = bufA + (size_t)total;

    dim3 grid(WID/64, HEI/64, B), block(256);

    // 41 ops total (t=0..40): 5 passes of K=8, then one K=1.
    pass_kernel<8,12><<<grid, block, 0, stream>>>(img,  bufA, skel, 0, 1); // t=0..7,  out E^8
    pass_kernel<8,12><<<grid, block, 0, stream>>>(bufA, bufB, skel, 1, 1); // t=8..15, out E^16
    pass_kernel<8,12><<<grid, block, 0, stream>>>(bufB, bufA, skel, 1, 1); // t=16..23, out E^24
    pass_kernel<8,12><<<grid, block, 0, stream>>>(bufA, bufB, skel, 1, 1); // t=24..31, out E^32
    pass_kernel<8,12><<<grid, block, 0, stream>>>(bufB, bufA, skel, 1, 1); // t=32..39, out E^40
    pass_kernel<1,4><<<grid, block, 0, stream>>>(bufA, nullptr, skel, 1, 0); // t=40
}

// Round 5
// 373.846 us; speedup vs baseline: 2.8784x; 1.0132x over previous
//
#include <hip/hip_runtime.h>
#include <math.h>

#define WID 1024
#define HEI 1024
#define OUTC 48      // output cols per wave (full bands)
#define HALOC 8      // halo lanes each side (supports K<=7)
#define BH 32        // output rows per wave
#define CB 22        // col bands: 21*48 + 16 = 1024 (last band outputs 16 cols)
#define RB (HEI/BH)  // 32

// Fused K-iteration pass, zero LDS. Input img_in = E^{t0}; applies ops
// t0..t0+K-1 to skel; optionally writes E^{t0+K} (WIMG). FIRST => skel starts 0.
template<int K, bool FIRST, bool WIMG>
__global__ __launch_bounds__(256)
void pass_kernel(const float* __restrict__ img_in, float* __restrict__ img_out,
                 float* __restrict__ skel, int nwaves)
{
    const int lane = threadIdx.x & 63;
    const int wid  = blockIdx.x*4 + (threadIdx.x >> 6);
    if (wid >= nwaves) return;
    const int perImg = CB*RB;
    const int b   = wid / perImg;
    const int rem = wid - b*perImg;
    const int cb  = rem % CB;
    const int rb  = rem / CB;
    const int outc = (WID - cb*OUTC < OUTC) ? (WID - cb*OUTC) : OUTC;  // 48 or 16
    const int x0  = cb*OUTC - HALOC;
    const int r0  = rb*BH;
    const int x   = x0 + lane;
    const bool colIn   = ((unsigned)x < (unsigned)WID);
    const bool outLane = (lane >= HALOC) && (lane < HALOC + outc);
    const size_t base = (size_t)b*HEI*WID;
    const float* imgp = img_in + base;
    const float INF = INFINITY;

    // stage rolling windows: stage j in [0,K]; wd=newest row (i-j), wc=i-j-1, wu=i-j-2
    float wu[K+1], wc[K+1], wd[K+1];
    float sk[K];                    // skel ring: sk[t] = row i-2-t
    #pragma unroll
    for (int j = 0; j <= K; ++j) { wu[j]=INF; wc[j]=INF; wd[j]=INF; }
    #pragma unroll
    for (int t = 0; t < K; ++t) sk[t] = 0.f;

    const int i0 = r0 - K - 1;
    const int isteps = BH + 2*K + 2;

    // prefetched values for the current step
    float vcur = (colIn && (unsigned)i0 < (unsigned)HEI)
               ? imgp[(size_t)i0*WID + x] : INF;
    float scur = 0.f;
    {
        int sr = i0 - 2;
        if (!FIRST && colIn && sr >= r0 && sr < r0+BH)
            scur = skel[base + (size_t)sr*WID + x];
    }

    #pragma unroll 1
    for (int s = 0; s < isteps; ++s) {
        const int i = i0 + s;

        // ---- issue next step's loads (hidden under this step's VALU) ----
        float vnext = INF;
        {
            int rn = i + 1;
            if (colIn && (unsigned)rn < (unsigned)HEI)
                vnext = imgp[(size_t)rn*WID + x];
        }
        float snext = 0.f;
        {
            int sr = i - 1;              // next step's (i+1)-2
            if (!FIRST && colIn && sr >= r0 && sr < r0+BH)
                snext = skel[base + (size_t)sr*WID + x];
        }

        // ---- stage 0 (img) shift ----
        wu[0] = wc[0]; wc[0] = wd[0]; wd[0] = vcur;

        // ---- erode stages j=1..K: new row i-j from stage j-1 window ----
        #pragma unroll
        for (int j = 1; j <= K; ++j) {
            const int rj = i - j;
            float ce = wc[j-1], up = wu[j-1], dn = wd[j-1];
            float lf = __shfl_up(ce, 1, 64);
            float rt = __shfl_down(ce, 1, 64);
            float nj = fminf(fminf(fminf(up, dn), ce), fminf(lf, rt));
            nj = ((unsigned)rj < (unsigned)HEI) ? nj : INF;   // row pad (+inf)
            nj = colIn ? nj : INF;                            // col pad (+inf)
            wu[j] = wc[j]; wc[j] = wd[j]; wd[j] = nj;
        }

        // ---- skel ring shift; fresh row i-2 enters at slot 0 ----
        #pragma unroll
        for (int t = K-1; t >= 1; --t) sk[t] = sk[t-1];
        sk[0] = scur;

        // ---- ops t=0..K-1: row ro=i-2-t; d = dilate3x3(E^{t+1}); skel update ----
        #pragma unroll
        for (int t = 0; t < K; ++t) {
            const int ro = i - 2 - t;
            float um = (ro >= 1)      ? wu[t+1] : -INF;   // row ro-1
            float dm = (ro <= HEI-2)  ? wd[t+1] : -INF;   // row ro+1
            float vm = fmaxf(fmaxf(um, dm), wc[t+1]);     // row ro
            vm = colIn ? vm : -INF;                       // dilate col pad (-inf)
            float hl = __shfl_up(vm, 1, 64);
            float hr = __shfl_down(vm, 1, 64);
            float d  = fmaxf(fmaxf(hl, hr), vm);
            float e1 = wu[t];                             // E^t row ro
            float delta = fmaxf(e1 - d, 0.f);
            float sv = sk[t];
            sk[t] = sv + fmaxf(delta - sv*delta, 0.f);
        }

        // ---- stores: skel row i-K-1 (final after t=K-1), E^K row i-K ----
        {
            int rs = i - K - 1;
            if (outLane && rs >= r0 && rs < r0+BH)
                skel[base + (size_t)rs*WID + x] = sk[K-1];
        }
        if (WIMG) {
            int re = i - K;
            if (outLane && re >= r0 && re < r0+BH)
                img_out[base + (size_t)re*WID + x] = wd[K];
        }

        vcur = vnext; scur = snext;
    }
}

extern "C" void kernel_launch(void* const* d_in, const int* in_sizes, int n_in,
                              void* d_out, int out_size, void* d_ws, size_t ws_size,
                              hipStream_t stream)
{
    const float* img = (const float*)d_in[0];
    float* skel = (float*)d_out;
    const int total = in_sizes[0];
    const int B = total / (HEI*WID);

    float* bufA = (float*)d_ws;
    float* bufB = bufA + (size_t)total;

    const int nw = B * CB * RB;
    const int blocks = (nw + 3) / 4;

    // 41 ops (t=0..40): 5 passes of K=7, then K=6.
    pass_kernel<7,true, true ><<<blocks,256,0,stream>>>(img,  bufA, skel, nw); // t=0..6,  out E^7
    pass_kernel<7,false,true ><<<blocks,256,0,stream>>>(bufA, bufB, skel, nw); // t=7..13, out E^14
    pass_kernel<7,false,true ><<<blocks,256,0,stream>>>(bufB, bufA, skel, nw); // t=14..20, out E^21
    pass_kernel<7,false,true ><<<blocks,256,0,stream>>>(bufA, bufB, skel, nw); // t=21..27, out E^28
    pass_kernel<7,false,true ><<<blocks,256,0,stream>>>(bufB, bufA, skel, nw); // t=28..34, out E^35
    pass_kernel<6,false,false><<<blocks,256,0,stream>>>(bufA, nullptr, skel, nw); // t=35..40
}

// Round 6
// 347.429 us; speedup vs baseline: 3.0973x; 1.0760x over previous
//
#include <hip/hip_runtime.h>
#include <math.h>

#define WID 1024
#define HEI 1024
#define OUTC 48      // output cols per wave (full bands)
#define HALOC 8      // halo lanes each side (supports K<=7)
#define BH 32        // output rows per wave
#define CB 22        // col bands: 21*48 + 16 = 1024 (last band outputs 16 cols)
#define RB (HEI/BH)  // 32

// lane +/-1 neighbor exchange via DPP wave shifts (VALU, no DS pipe).
// Direction symmetric use (min/max of both) => mapping direction irrelevant.
__device__ __forceinline__ float lane_up1(float v) {   // lane i <- lane i-1
#if __has_builtin(__builtin_amdgcn_update_dpp)
    return __int_as_float(__builtin_amdgcn_update_dpp(
        __float_as_int(v), __float_as_int(v), 0x138, 0xF, 0xF, false)); // wave_shr:1
#else
    return __shfl_up(v, 1, 64);
#endif
}
__device__ __forceinline__ float lane_dn1(float v) {   // lane i <- lane i+1
#if __has_builtin(__builtin_amdgcn_update_dpp)
    return __int_as_float(__builtin_amdgcn_update_dpp(
        __float_as_int(v), __float_as_int(v), 0x130, 0xF, 0xF, false)); // wave_shl:1
#else
    return __shfl_down(v, 1, 64);
#endif
}

// Fused K-iteration columns-in-lanes pipeline. MASKED=false for interior waves
// (no image-boundary handling needed; all forces provably never trigger).
template<int K, bool FIRST, bool WIMG, bool MASKED>
__device__ __forceinline__ void pass_body(const float* __restrict__ imgp,
                                          float* __restrict__ outi,
                                          float* __restrict__ outs,
                                          int r0, int x, bool colIn, bool outLane)
{
    const float INF = INFINITY;
    float wu[K+1], wc[K+1], wd[K+1];   // stage j rolling window: rows i-j-2, i-j-1, i-j
    float sk[K];                       // skel ring: sk[t] = row i-2-t
    #pragma unroll
    for (int j = 0; j <= K; ++j) { wu[j]=INF; wc[j]=INF; wd[j]=INF; }
    #pragma unroll
    for (int t = 0; t < K; ++t) sk[t] = 0.f;

    const int i0 = r0 - K - 1;
    const int isteps = BH + 2*K + 2;

    float vcur, scur = 0.f;
    if (MASKED)
        vcur = (colIn && (unsigned)i0 < (unsigned)HEI) ? imgp[(size_t)i0*WID + x] : INF;
    else
        vcur = imgp[(size_t)i0*WID + x];
    if (!FIRST) {
        int sr = i0 - 2;
        if (MASKED) scur = (colIn && sr >= r0 && sr < r0+BH) ? outs[(size_t)sr*WID + x] : 0.f;
        else        scur = outs[(size_t)sr*WID + x];   // rows outside band: discarded
    }

    #pragma unroll 1
    for (int s = 0; s < isteps; ++s) {
        const int i = i0 + s;

        // next step's loads (hidden under this step's VALU)
        float vnext, snext = 0.f;
        {
            int rn = i + 1;
            if (MASKED) vnext = (colIn && (unsigned)rn < (unsigned)HEI)
                              ? imgp[(size_t)rn*WID + x] : INF;
            else        vnext = imgp[(size_t)rn*WID + x];
        }
        if (!FIRST) {
            int sr = i - 1;
            if (MASKED) snext = (colIn && sr >= r0 && sr < r0+BH)
                              ? outs[(size_t)sr*WID + x] : 0.f;
            else        snext = outs[(size_t)sr*WID + x];
        }

        // stage 0 (img) shift
        wu[0] = wc[0]; wc[0] = wd[0]; wd[0] = vcur;

        // erode stages j=1..K: new row i-j from stage j-1 window
        #pragma unroll
        for (int j = 1; j <= K; ++j) {
            float ce = wc[j-1];
            float lf = lane_up1(ce);
            float rt = lane_dn1(ce);
            float nj = fminf(fminf(fminf(wu[j-1], wd[j-1]), ce), fminf(lf, rt));
            if (MASKED) {
                int rj = i - j;
                nj = ((unsigned)rj < (unsigned)HEI) ? nj : INF;  // row pad (+inf)
                nj = colIn ? nj : INF;                           // col pad (+inf)
            }
            wu[j] = wc[j]; wc[j] = wd[j]; wd[j] = nj;
        }

        // skel ring shift; fresh row i-2 enters
        #pragma unroll
        for (int t = K-1; t >= 1; --t) sk[t] = sk[t-1];
        sk[0] = FIRST ? 0.f : scur;

        // ops t=0..K-1: row ro=i-2-t; d = dilate3x3(E^{t+1}); skel update
        #pragma unroll
        for (int t = 0; t < K; ++t) {
            float um = wu[t+1], dm = wd[t+1];
            if (MASKED) {
                int ro = i - 2 - t;
                um = (ro >= 1)     ? um : -INF;
                dm = (ro <= HEI-2) ? dm : -INF;
            }
            float vm = fmaxf(fmaxf(um, dm), wc[t+1]);
            if (MASKED) vm = colIn ? vm : -INF;
            float hl = lane_up1(vm);
            float hr = lane_dn1(vm);
            float d  = fmaxf(fmaxf(hl, hr), vm);
            float e1 = wu[t];
            float delta = fmaxf(e1 - d, 0.f);
            float sv = sk[t];
            sk[t] = sv + fmaxf(delta - sv*delta, 0.f);
        }

        // stores: skel row i-K-1 (final), E^K row i-K
        {
            int rs = i - K - 1;
            if (rs >= r0 && rs < r0+BH && outLane)
                outs[(size_t)rs*WID + x] = sk[K-1];
        }
        if (WIMG) {
            int re = i - K;
            if (re >= r0 && re < r0+BH && outLane)
                outi[(size_t)re*WID + x] = wd[K];
        }

        vcur = vnext; scur = snext;
    }
}

template<int K, bool FIRST, bool WIMG>
__global__ __launch_bounds__(256)
void pass_kernel(const float* __restrict__ img_in, float* __restrict__ img_out,
                 float* __restrict__ skel, int nwaves)
{
    const int lane = threadIdx.x & 63;
    const int wid  = blockIdx.x*4 + (threadIdx.x >> 6);
    if (wid >= nwaves) return;
    const int perImg = CB*RB;
    const int b   = wid / perImg;
    const int rem = wid - b*perImg;
    const int cb  = rem % CB;
    const int rb  = rem / CB;
    const int outc = (WID - cb*OUTC < OUTC) ? (WID - cb*OUTC) : OUTC;  // 48 or 16
    const int x0  = cb*OUTC - HALOC;
    const int r0  = rb*BH;
    const int x   = x0 + lane;
    const bool colIn   = ((unsigned)x < (unsigned)WID);
    const bool outLane = (lane >= HALOC) && (lane < HALOC + outc);
    const size_t base = (size_t)b*HEI*WID;

    const float* imgp = img_in + base;
    float* outi = WIMG ? (img_out + base) : nullptr;
    float* outs = skel + base;

    // interior waves: no image-boundary effects anywhere in their sweep
    const bool fast = (cb >= 1) && (cb <= CB-2) && (rb >= 1) && (rb <= RB-2);
    if (fast)
        pass_body<K, FIRST, WIMG, false>(imgp, outi, outs, r0, x, true, outLane);
    else
        pass_body<K, FIRST, WIMG, true >(imgp, outi, outs, r0, x, colIn, outLane);
}

extern "C" void kernel_launch(void* const* d_in, const int* in_sizes, int n_in,
                              void* d_out, int out_size, void* d_ws, size_t ws_size,
                              hipStream_t stream)
{
    const float* img = (const float*)d_in[0];
    float* skel = (float*)d_out;
    const int total = in_sizes[0];
    const int B = total / (HEI*WID);

    float* bufA = (float*)d_ws;
    float* bufB = bufA + (size_t)total;

    const int nw = B * CB * RB;
    const int blocks = (nw + 3) / 4;

    // 41 ops (t=0..40): 5 passes of K=7, then K=6.
    pass_kernel<7,true, true ><<<blocks,256,0,stream>>>(img,  bufA, skel, nw); // t=0..6
    pass_kernel<7,false,true ><<<blocks,256,0,stream>>>(bufA, bufB, skel, nw); // t=7..13
    pass_kernel<7,false,true ><<<blocks,256,0,stream>>>(bufB, bufA, skel, nw); // t=14..20
    pass_kernel<7,false,true ><<<blocks,256,0,stream>>>(bufA, bufB, skel, nw); // t=21..27
    pass_kernel<7,false,true ><<<blocks,256,0,stream>>>(bufB, bufA, skel, nw); // t=28..34
    pass_kernel<6,false,false><<<blocks,256,0,stream>>>(bufA, nullptr, skel, nw); // t=35..40
}